// Round 12
// baseline (380.795 us; speedup 1.0000x reference)
//
#include <hip/hip_runtime.h>
#include <hip/hip_bf16.h>

// Chamfer distance, B=16, N=M=4096, D=3, fp32 — one-pass MFMA, both mins.
// Round-12: r4 inner loop VERBATIM at 6 waves/SIMD (occupancy experiment).
//
// Evidence ledger (rounds 0-11):
//  * Main kernel is LATENCY-bound; occupancy is the binding constraint:
//    2 blk/CU -> main ~28-35 (r3/r11), 4 blk/CU -> ~27-29 (r4, best total
//    78.67). Per-step work composition (2 vs 4 MFMA) mattered less (r11
//    regressed at 2/CU despite half the steps).
//  * SPILL RULE: the r4 loop body allocates 84 VGPR (measured r2/r3); any
//    variant exceeding its cap spilled catastrophically (r1/r2/r5/r7/r10).
//  * THIS round: same body at __launch_bounds__(256,6) (cap 85 >= 84),
//    LDS 20KB (CHUNKC=256 dbuf 16KB + 1024-col colpart 4KB), grid 2048
//    (q4 x b16 x strip32) -> 6 blocks/CU resident. +50% latency hiding.
//    Health check: VGPR_Count must be ~84, main < 30us. If spill -> revert
//    to r4 verbatim.
//   row-min -> cham_x : rm[16] accum -> shfl fold -> colpart transpose ->
//                       clamped atomicMin wsR           (r4-verbatim)
//   col-min -> cham_y : tree16 -> 64-lane LDS atomicMin colpart ->
//                       block-end global atomicMin wsC  (r4-verbatim)
// finish: 32 blocks sum both 256KB planes -> atomicAdd out (r4-verbatim).
// 4 dispatches: memset out, memset ws 512KB, main, finish.

#define BATCH   16
#define NPTS    4096
#define NSTRIPS 32                 // 128 rows per block
#define NQ      4                  // col quarters
#define COLS_PB 1024
#define CHUNKC  256
#define NCHUNKS (COLS_PB / CHUNKC) // 4
#define NSTEP   (CHUNKC / 64)      // 4

typedef __attribute__((ext_vector_type(8)))  short short8;
typedef __attribute__((ext_vector_type(16))) float float16;

union U4S8 { uint4 u; short8 s; };

__device__ inline unsigned int bfb(float v) {
    __hip_bfloat16 h = __float2bfloat16(v);
    unsigned short u; __builtin_memcpy(&u, &h, 2);
    return (unsigned int)u;
}
__device__ inline float bff(float v) { return __bfloat162float(__float2bfloat16(v)); }

#define ONEB 0x3F80u

// A (query) slots: [xh yh zh xh yh zh xl yl | zl fh fl 1 1 0 0 0]
__device__ inline void buildA(float x, float y, float z, uint4& w0, uint4& w1) {
    float xhf = bff(x), yhf = bff(y), zhf = bff(z);
    float f = fmaf(x, x, fmaf(y, y, z * z));
    float fhf = bff(f);
    unsigned xh = bfb(xhf), yh = bfb(yhf), zh = bfb(zhf);
    unsigned xl = bfb(x - xhf), yl = bfb(y - yhf), zl = bfb(z - zhf);
    unsigned fh = bfb(fhf), fl = bfb(f - fhf);
    w0 = make_uint4(xh | (yh << 16), zh | (xh << 16),
                    yh | (zh << 16), xl | (yl << 16));
    w1 = make_uint4(zl | (fh << 16), fl | (ONEB << 16), ONEB, 0u);
}

// B (target) slots: [-2xh -2yh -2zh -2xl -2yl -2zl -2xh -2yh | -2zh 1 1 fh fl 0 0 0]
__device__ inline void buildB(float x, float y, float z, uint4& w0, uint4& w1) {
    float xhf = bff(x), yhf = bff(y), zhf = bff(z);
    float f = fmaf(x, x, fmaf(y, y, z * z));
    float fhf = bff(f);
    unsigned a = bfb(-2.0f * xhf), b = bfb(-2.0f * yhf), c = bfb(-2.0f * zhf);
    unsigned d = bfb(-2.0f * (x - xhf)), e = bfb(-2.0f * (y - yhf)),
             g = bfb(-2.0f * (z - zhf));
    unsigned fh = bfb(fhf), fl = bfb(f - fhf);
    w0 = make_uint4(a | (b << 16), c | (d << 16),
                    e | (g << 16), a | (b << 16));
    w1 = make_uint4(c | (ONEB << 16), ONEB | (fh << 16), fl, 0u);
}

// min over the 16 regs (this half's 16 rows) of one 32x32 MFMA result.
__device__ inline float tree16(const float16& a) {
    float m0 = fminf(fminf(a[0],  a[1]),  a[2]);    // v_min3
    float m1 = fminf(fminf(a[3],  a[4]),  a[5]);
    float m2 = fminf(fminf(a[6],  a[7]),  a[8]);
    float m3 = fminf(fminf(a[9],  a[10]), a[11]);
    float m4 = fminf(fminf(a[12], a[13]), a[14]);
    float p0 = fminf(fminf(m0, m1), a[15]);
    float p1 = fminf(fminf(m2, m3), m4);
    return fminf(p0, p1);
}

__global__ __launch_bounds__(256, 6) void chamfer_main(
    const float* __restrict__ src, const float* __restrict__ tgt,
    unsigned* __restrict__ wsC, unsigned* __restrict__ wsR)
{
    __shared__ uint4    sbuf[2][2][CHUNKC];   // [buf][half][pt] = 16 KB
    __shared__ unsigned colpart[COLS_PB];     // 4 KB; LDS 20KB -> 6 blk/CU

    int blk = blockIdx.x;
    const int strip = blk & (NSTRIPS - 1); blk >>= 5;
    const int b     = blk & 15;            blk >>= 4;
    const int q     = blk;                 // col quarter 0..3
    const int qoff  = q * COLS_PB;

    const int t    = threadIdx.x;
    const int lane = t & 63;
    const int w    = t >> 6;
    const int h    = lane >> 5;
    const int l5   = lane & 31;

    const float* Araw = src + (size_t)b * NPTS * 3;   // rows (queries)
    const float* Braw = tgt + (size_t)b * NPTS * 3;   // cols (targets)

    // A fragment: one 32-row group per wave (128 rows per block). SPILL RULE.
    short8 afr;
    {
        int row = strip * 128 + w * 32 + l5;
        uint4 w0, w1;
        buildA(Araw[3 * row], Araw[3 * row + 1], Araw[3 * row + 2], w0, w1);
        U4S8 tt; tt.u = h ? w1 : w0;
        afr = tt.s;
    }

    // init block-local col-min plane (4 entries per thread)
#pragma unroll
    for (int i = 0; i < COLS_PB / 256; i++) colpart[t + i * 256] = 0xFFFFFFFFu;

    // Pipelined B staging: raw loads (regs) early, convert + ds_write late.
    float nx[3];
    auto loadRaw = [&](int c) {
        int p = qoff + c * CHUNKC + t;     // 256 pts per chunk, 1 per thread
        nx[0] = Braw[3 * p + 0];
        nx[1] = Braw[3 * p + 1];
        nx[2] = Braw[3 * p + 2];
    };
    auto convertWrite = [&](int bi) {
        uint4 w0, w1;
        buildB(nx[0], nx[1], nx[2], w0, w1);
        sbuf[bi][0][t] = w0;
        sbuf[bi][1][t] = w1;
    };

    const float16 z16 = {0.f,0.f,0.f,0.f,0.f,0.f,0.f,0.f,
                         0.f,0.f,0.f,0.f,0.f,0.f,0.f,0.f};
    float rm[16];
#pragma unroll
    for (int r = 0; r < 16; r++) rm[r] = 1e30f;

    loadRaw(0);
    convertWrite(0);
    for (int c = 0; c < NCHUNKS; c++) {
        __syncthreads();              // buf[c&1] written; prior-iter reads done
        if (c + 1 < NCHUNKS) loadRaw(c + 1);   // issue, don't wait
        const int bi = c & 1;

        U4S8 c0, c1, n0, n1;
        c0.u = sbuf[bi][h][l5];
        c1.u = sbuf[bi][h][32 + l5];
#pragma unroll 4
        for (int j = 0; j < NSTEP; j++) {
            int nj = (j + 1) & (NSTEP - 1);        // wrap re-read: harmless
            n0.u = sbuf[bi][h][nj * 64 + l5];
            n1.u = sbuf[bi][h][nj * 64 + 32 + l5];
            float16 a0 = __builtin_amdgcn_mfma_f32_32x32x16_bf16(afr, c0.s, z16, 0, 0, 0);
            float16 a1 = __builtin_amdgcn_mfma_f32_32x32x16_bf16(afr, c1.s, z16, 0, 0, 0);
#pragma unroll
            for (int r = 0; r < 16; r++)
                rm[r] = fminf(fminf(a0[r], a1[r]), rm[r]);     // v_min3
            // col-mins over this half's 16 rows; 64-lane LDS atomicMin
            // merges halves and waves (r4-identical).
            float cm0 = tree16(a0);
            float cm1 = tree16(a1);
            const int col = c * CHUNKC + j * 64 + l5;
            atomicMin(&colpart[col],      __float_as_uint(fmaxf(cm0, 0.0f)));
            atomicMin(&colpart[col + 32], __float_as_uint(fmaxf(cm1, 0.0f)));
            c0 = n0; c1 = n1;
        }
        if (c + 1 < NCHUNKS) convertWrite((c + 1) & 1);      // vmcnt hidden
    }

    __syncthreads();                       // all col atomics visible

    // merge block-local col-mins into the global plane (4 per thread)
#pragma unroll
    for (int i = 0; i < COLS_PB / 256; i++) {
        const int idx = t + i * 256;
        atomicMin(&wsC[(size_t)b * NPTS + qoff + idx], colpart[idx]);
    }

    // Row-min partial (this block's 1024 cols): fold 32 col-slots across
    // lanes (masks 1..16; h-halves hold disjoint row sets -> no mask 32).
#pragma unroll
    for (int mask = 1; mask <= 16; mask <<= 1)
#pragma unroll
        for (int r = 0; r < 16; r++)
            rm[r] = fminf(rm[r], __shfl_xor(rm[r], mask, 64));

    // transpose via LDS (reuse colpart[0:128) after its merge-reads), then
    // coalesced clamped atomicMin into wsR.
    __syncthreads();                 // colpart merge reads done
    if (l5 == 0) {
#pragma unroll
        for (int r = 0; r < 16; r++) {
            const int row = w * 32 + (r & 3) + 8 * (r >> 2) + 4 * h;
            colpart[row] = __float_as_uint(fmaxf(rm[r], 0.0f));
        }
    }
    __syncthreads();
    if (t < 128)
        atomicMin(&wsR[(size_t)b * NPTS + strip * 128 + t], colpart[t]);
}

// ---- finish: 32 blocks (XCD-spread) sum both planes -> atomicAdd out
__global__ __launch_bounds__(256) void finish_reduce(
    const unsigned* __restrict__ ws, float* __restrict__ out)
{
    __shared__ float wsum[4];
    const int tg = blockIdx.x * 256 + threadIdx.x;   // 8192 threads
    float v = 0.0f;
#pragma unroll
    for (int i = 0; i < 16; i++)                     // 131072 cells total
        v += __uint_as_float(ws[tg + i * 8192]);
#pragma unroll
    for (int mask = 1; mask <= 32; mask <<= 1) v += __shfl_xor(v, mask, 64);
    if ((threadIdx.x & 63) == 0) wsum[threadIdx.x >> 6] = v;
    __syncthreads();
    if (threadIdx.x == 0)
        atomicAdd(out, (wsum[0] + wsum[1] + wsum[2] + wsum[3]) * (1.0f / (float)NPTS));
}

// ---------------------------------------------------------------- launch
extern "C" void kernel_launch(void* const* d_in, const int* in_sizes, int n_in,
                              void* d_out, int out_size, void* d_ws, size_t ws_size,
                              hipStream_t stream)
{
    const float* src = (const float*)d_in[0];
    const float* tgt = (const float*)d_in[1];
    float* out = (float*)d_out;
    unsigned* wsC = (unsigned*)d_ws;                      // 256 KB
    unsigned* wsR = wsC + (size_t)BATCH * NPTS;           // 256 KB

    hipMemsetAsync(out, 0, sizeof(float), stream);
    hipMemsetAsync(d_ws, 0xFF, (size_t)2 * BATCH * NPTS * sizeof(unsigned), stream);
    chamfer_main <<<NQ * BATCH * NSTRIPS, 256, 0, stream>>>(src, tgt, wsC, wsR);
    finish_reduce<<<32, 256, 0, stream>>>((const unsigned*)d_ws, out);
}

// Round 13
// 77.755 us; speedup vs baseline: 4.8973x; 4.8973x over previous
//
#include <hip/hip_runtime.h>
#include <hip/hip_bf16.h>

// Chamfer distance, B=16, N=M=4096, D=3, fp32 — one-pass MFMA, both mins.
// FINAL (round-13) = round-4 configuration VERBATIM: the empirical optimum
// of this session (78.67us total; every departure regressed).
//
// Evidence ledger (rounds 0-12), for future sessions:
//  * Total = ~40us harness poison-fill floor (84% HBM peak, untouchable
//    from kernel_launch) + ~38.7us kernel chain.
//  * Occupancy axis closed: 2 waves/SIMD latency-bound (r0/r11 main ~35),
//    4 waves/SIMD best (this kernel, main ~27, VGPR allocs 84 under the
//    128 cap), 6 waves/SIMD -> allocator rounds 85-cap DOWN to 40 VGPR ->
//    catastrophic scratch spill (r12: main 340us, 1.5GB HBM traffic).
//  * SPILL is the universal failure mode (r1/r2/r5/r7/r10/r12): signature
//    = hundreds-of-MB FETCH/WRITE vs ~MB logical, MfmaUtil<2%, sometimes
//    L2-resident (invisible to TCC, r10). Causes: multi-row-group
//    accumulators, in-loop shfl/divergence, epilogue regalloc perturbation,
//    tight launch_bounds.
//  * Merge alternatives all lost: plain-store 8.5MB planes +4.7us (r9),
//    1-block finish +20us (r5/r6), fused last-block finish 3x main (r10).
//  * One-pass math (row+col mins from one d2 pass) verified exact 10x
//    (absmax=0 every round).
// Structure: grid q2 x b16 x strip32 = 1024 blocks x 256thr; block =
// 128 rows x 2048 cols; CHUNKC=512 double-buffered LDS staging (32KB) +
// 8KB colpart = 40KB -> 4 blocks/CU; per step: 2 ds_read -> 2 MFMA ->
// 16 v_min3 row-accum -> 2 tree16 -> 2 64-lane LDS atomicMin.
//   row-min -> cham_x : rm[16] -> shfl fold -> transpose -> atomicMin wsR
//   col-min -> cham_y : colpart -> block-end global atomicMin wsC
// finish: 128 threads x 32 blocks... (32-block finish, XCD-spread).
// 4 dispatches: memset out 4B, memset ws 512KB, main, finish.

#define BATCH   16
#define NPTS    4096
#define NSTRIPS 32                 // 128 rows per block
#define NH      2                  // col halves
#define COLS_PB 2048               // cols per block
#define CHUNKC  512
#define NCHUNKS (COLS_PB / CHUNKC) // 4
#define NSTEP   (CHUNKC / 64)      // 8 j2-steps per chunk

typedef __attribute__((ext_vector_type(8)))  short short8;
typedef __attribute__((ext_vector_type(16))) float float16;

union U4S8 { uint4 u; short8 s; };

__device__ inline unsigned int bfb(float v) {
    __hip_bfloat16 h = __float2bfloat16(v);
    unsigned short u; __builtin_memcpy(&u, &h, 2);
    return (unsigned int)u;
}
__device__ inline float bff(float v) { return __bfloat162float(__float2bfloat16(v)); }

#define ONEB 0x3F80u

// A (query) slots: [xh yh zh xh yh zh xl yl | zl fh fl 1 1 0 0 0]
__device__ inline void buildA(float x, float y, float z, uint4& w0, uint4& w1) {
    float xhf = bff(x), yhf = bff(y), zhf = bff(z);
    float f = fmaf(x, x, fmaf(y, y, z * z));
    float fhf = bff(f);
    unsigned xh = bfb(xhf), yh = bfb(yhf), zh = bfb(zhf);
    unsigned xl = bfb(x - xhf), yl = bfb(y - yhf), zl = bfb(z - zhf);
    unsigned fh = bfb(fhf), fl = bfb(f - fhf);
    w0 = make_uint4(xh | (yh << 16), zh | (xh << 16),
                    yh | (zh << 16), xl | (yl << 16));
    w1 = make_uint4(zl | (fh << 16), fl | (ONEB << 16), ONEB, 0u);
}

// B (target) slots: [-2xh -2yh -2zh -2xl -2yl -2zl -2xh -2yh | -2zh 1 1 fh fl 0 0 0]
__device__ inline void buildB(float x, float y, float z, uint4& w0, uint4& w1) {
    float xhf = bff(x), yhf = bff(y), zhf = bff(z);
    float f = fmaf(x, x, fmaf(y, y, z * z));
    float fhf = bff(f);
    unsigned a = bfb(-2.0f * xhf), b = bfb(-2.0f * yhf), c = bfb(-2.0f * zhf);
    unsigned d = bfb(-2.0f * (x - xhf)), e = bfb(-2.0f * (y - yhf)),
             g = bfb(-2.0f * (z - zhf));
    unsigned fh = bfb(fhf), fl = bfb(f - fhf);
    w0 = make_uint4(a | (b << 16), c | (d << 16),
                    e | (g << 16), a | (b << 16));
    w1 = make_uint4(c | (ONEB << 16), ONEB | (fh << 16), fl, 0u);
}

// min over the 16 regs (this half's 16 rows) of one 32x32 MFMA result.
__device__ inline float tree16(const float16& a) {
    float m0 = fminf(fminf(a[0],  a[1]),  a[2]);    // v_min3
    float m1 = fminf(fminf(a[3],  a[4]),  a[5]);
    float m2 = fminf(fminf(a[6],  a[7]),  a[8]);
    float m3 = fminf(fminf(a[9],  a[10]), a[11]);
    float m4 = fminf(fminf(a[12], a[13]), a[14]);
    float p0 = fminf(fminf(m0, m1), a[15]);
    float p1 = fminf(fminf(m2, m3), m4);
    return fminf(p0, p1);
}

__global__ __launch_bounds__(256, 4) void chamfer_main(
    const float* __restrict__ src, const float* __restrict__ tgt,
    unsigned* __restrict__ wsC, unsigned* __restrict__ wsR)
{
    __shared__ uint4 sbuf[2][2][CHUNKC];     // [buf][half][pt] = 32 KB
    __shared__ unsigned colpart[COLS_PB];    // 8 KB (rowbuf reuses [0:128))

    int blk = blockIdx.x;
    const int strip = blk & (NSTRIPS - 1); blk >>= 5;
    const int b     = blk & 15;            blk >>= 4;
    const int q     = blk;                 // col half 0/1
    const int qoff  = q * COLS_PB;

    const int t    = threadIdx.x;
    const int lane = t & 63;
    const int w    = t >> 6;
    const int h    = lane >> 5;
    const int l5   = lane & 31;

    const float* Araw = src + (size_t)b * NPTS * 3;   // rows (queries)
    const float* Braw = tgt + (size_t)b * NPTS * 3;   // cols (targets)

    // A fragment: one 32-row group per wave (128 rows per block)
    short8 afr;
    {
        int row = strip * 128 + w * 32 + l5;
        uint4 w0, w1;
        buildA(Araw[3 * row], Araw[3 * row + 1], Araw[3 * row + 2], w0, w1);
        U4S8 tt; tt.u = h ? w1 : w0;
        afr = tt.s;
    }

    // init block-local col-min plane (8 entries per thread)
#pragma unroll
    for (int i = 0; i < COLS_PB / 256; i++) colpart[t + i * 256] = 0xFFFFFFFFu;

    // Pipelined B staging: raw loads (regs) early, convert + ds_write late.
    float nx[2][3];
    auto loadRaw = [&](int c) {
#pragma unroll
        for (int k = 0; k < 2; k++) {
            int p = qoff + c * CHUNKC + t + k * 256;
            nx[k][0] = Braw[3 * p + 0];
            nx[k][1] = Braw[3 * p + 1];
            nx[k][2] = Braw[3 * p + 2];
        }
    };
    auto convertWrite = [&](int bi) {
#pragma unroll
        for (int k = 0; k < 2; k++) {
            int lp = t + k * 256;
            uint4 w0, w1;
            buildB(nx[k][0], nx[k][1], nx[k][2], w0, w1);
            sbuf[bi][0][lp] = w0;
            sbuf[bi][1][lp] = w1;
        }
    };

    const float16 z16 = {0.f,0.f,0.f,0.f,0.f,0.f,0.f,0.f,
                         0.f,0.f,0.f,0.f,0.f,0.f,0.f,0.f};
    float rm[16];
#pragma unroll
    for (int r = 0; r < 16; r++) rm[r] = 1e30f;

    loadRaw(0);
    convertWrite(0);
    for (int c = 0; c < NCHUNKS; c++) {
        __syncthreads();              // buf[c&1] written; prior-iter reads done
        if (c + 1 < NCHUNKS) loadRaw(c + 1);   // issue, don't wait
        const int bi = c & 1;

        U4S8 c0, c1, n0, n1;
        c0.u = sbuf[bi][h][l5];
        c1.u = sbuf[bi][h][32 + l5];
#pragma unroll 4
        for (int j = 0; j < NSTEP; j++) {
            int nj = (j + 1) & (NSTEP - 1);          // wrap re-read: harmless
            n0.u = sbuf[bi][h][nj * 64 + l5];
            n1.u = sbuf[bi][h][nj * 64 + 32 + l5];
            float16 a0 = __builtin_amdgcn_mfma_f32_32x32x16_bf16(afr, c0.s, z16, 0, 0, 0);
            float16 a1 = __builtin_amdgcn_mfma_f32_32x32x16_bf16(afr, c1.s, z16, 0, 0, 0);
#pragma unroll
            for (int r = 0; r < 16; r++)
                rm[r] = fminf(fminf(a0[r], a1[r]), rm[r]);     // v_min3
            // col-mins over this half's 16 rows; both halves atomicMin-merge
            float cm0 = tree16(a0);
            float cm1 = tree16(a1);
            const int col = c * CHUNKC + j * 64 + l5;         // block-local
            atomicMin(&colpart[col],      __float_as_uint(fmaxf(cm0, 0.0f)));
            atomicMin(&colpart[col + 32], __float_as_uint(fmaxf(cm1, 0.0f)));
            c0 = n0; c1 = n1;
        }
        if (c + 1 < NCHUNKS) convertWrite((c + 1) & 1);      // vmcnt hidden
    }

    // merge block-local col-mins into the global plane (8 per thread)
    __syncthreads();
#pragma unroll
    for (int i = 0; i < COLS_PB / 256; i++) {
        const int idx = t + i * 256;
        atomicMin(&wsC[(size_t)b * NPTS + qoff + idx], colpart[idx]);
    }

    // Row-min partial (over this block's 2048 cols): fold the 32 col-slots
    // across lanes (masks 1..16; halves hold disjoint row sets).
#pragma unroll
    for (int mask = 1; mask <= 16; mask <<= 1)
#pragma unroll
        for (int r = 0; r < 16; r++)
            rm[r] = fminf(rm[r], __shfl_xor(rm[r], mask, 64));

    // transpose via LDS (reuse colpart[0:128)), then coalesced atomicMin.
    __syncthreads();                 // colpart merge reads done
    if (l5 == 0) {
#pragma unroll
        for (int r = 0; r < 16; r++) {
            const int row = w * 32 + (r & 3) + 8 * (r >> 2) + 4 * h;
            colpart[row] = __float_as_uint(fmaxf(rm[r], 0.0f));
        }
    }
    __syncthreads();
    if (t < 128)
        atomicMin(&wsR[(size_t)b * NPTS + strip * 128 + t], colpart[t]);
}

// ---------------------- K2: sum col-min + row-min planes (2 x 256 KB)
__global__ __launch_bounds__(256) void finish_reduce(
    const unsigned* __restrict__ wsC, const unsigned* __restrict__ wsR,
    float* __restrict__ out)
{
    __shared__ float wsum[4];
    const int b = blockIdx.x;
    float v = 0.0f;
#pragma unroll
    for (int i = 0; i < 16; i++)
        v += __uint_as_float(wsC[(size_t)b * NPTS + threadIdx.x + i * 256]);
#pragma unroll
    for (int i = 0; i < 16; i++)
        v += __uint_as_float(wsR[(size_t)b * NPTS + threadIdx.x + i * 256]);
#pragma unroll
    for (int mask = 1; mask <= 32; mask <<= 1) v += __shfl_xor(v, mask, 64);
    if ((threadIdx.x & 63) == 0) wsum[threadIdx.x >> 6] = v;
    __syncthreads();
    if (threadIdx.x == 0)
        atomicAdd(out, (wsum[0] + wsum[1] + wsum[2] + wsum[3]) * (1.0f / (float)NPTS));
}

// ---------------------------------------------------------------- launch
extern "C" void kernel_launch(void* const* d_in, const int* in_sizes, int n_in,
                              void* d_out, int out_size, void* d_ws, size_t ws_size,
                              hipStream_t stream)
{
    const float* src = (const float*)d_in[0];
    const float* tgt = (const float*)d_in[1];
    float* out = (float*)d_out;
    unsigned* wsC = (unsigned*)d_ws;                      // 256 KB
    unsigned* wsR = wsC + (size_t)BATCH * NPTS;           // 256 KB

    hipMemsetAsync(out, 0, sizeof(float), stream);
    hipMemsetAsync(d_ws, 0xFF, (size_t)2 * BATCH * NPTS * sizeof(unsigned), stream);
    chamfer_main <<<NH * BATCH * NSTRIPS, 256, 0, stream>>>(src, tgt, wsC, wsR);
    finish_reduce<<<BATCH, 256, 0, stream>>>(wsC, wsR, out);
}